// Round 5
// baseline (322.029 us; speedup 1.0000x reference)
//
#include <hip/hip_runtime.h>
#include <hip/hip_bf16.h>

// RoIPool max over boolean cell masks (harness bf16-ifies floats AND bools).
// B=8, C=256, H=W=64 (HW=4096), N=128 cells (16/image).
// R10 (post-mortem R9: totals insensitive across R5/R7/R9 (86-90us); fill
// noise +-2us. Suspected defect in R9: __launch_bounds__(256,8) caps VGPR
// at 64 but peak live set ~70 (vmax16+pe8+po8+pmw8+f8) -> scratch spill,
// invisible below the top-5 cutoff. Fix + decouple detect from data loads):
//   1. pe/po arrays eliminated: fe/fo computed on the fly from raw w8[k]
//      (+16 VALU/thread, -16 live VGPRs -> ~48 live, genuinely fits 64 cap,
//      8 waves/SIMD, all 2048 blocks in one round).
//   2. detect dword issued FIRST: vmcnt drains oldest-first, so the ballot
//      now retires at vmcnt(4) with f0/f1/pa/pb still in flight (R9 drained
//      everything before the branch).
//   3. f32 cold path reloads branch-locally (no lifetimes across the join).
//   pack_masks: R9 verbatim (passed; speculative loads + byte-sniff detect).
// If this round still lands ~87-90 total, the ~82us floor is harness-owned
// (43us ws-poison fill + ~25us reset train + restores) -> ROOFLINE.

#define HW    4096
#define BIMG  8
#define CCH   256
#define NCELL 128

__device__ __forceinline__ void cell_range(const int* counts, int b, int& start, int& cnt) {
    start = 0;
    for (int i = 0; i < b; ++i) start += counts[i];
    if (start > NCELL) start = NCELL;
    cnt = counts[b];
    // jnp.repeat(..., total_repeat_length=N) pads with the last value:
    if (b == BIMG - 1 && start + cnt < NCELL) cnt = NCELL - start;
    if (cnt > 16) cnt = 16;
    if (start + cnt > NCELL) cnt = NCELL - start;
    if (cnt < 0) cnt = 0;
}

// ---- kernel 1: bit-pack masks. grid 128 x 256 threads = 32768 = BIMG*HW ----
__global__ __launch_bounds__(256)
void pack_masks(const void* __restrict__ maskv,
                const int* __restrict__ counts,
                unsigned short* __restrict__ packed) {
    const int tid = threadIdx.x;
    const int l   = tid & 63;
    const int idx = blockIdx.x * 256 + tid;      // b*HW + p
    const int b = idx >> 12;
    const int p = idx & (HW - 1);

    // --- ALL loads issued up front, independent; detect dwords first ---
    // (a) dtype detect: byte-lane OR over first 1 KiB (proven R3..R9)
    const unsigned* mw0 = (const unsigned*)maskv;
    const unsigned o0 = mw0[l * 4], o1 = mw0[l * 4 + 1],
                   o2 = mw0[l * 4 + 2], o3 = mw0[l * 4 + 3];
    // (b) speculative bf16-interp mask loads assuming start=b*16, cnt=16
    //     (actual harness layout; bf16 interp never exceeds the real buffer)
    const unsigned short* mh = (const unsigned short*)maskv + ((size_t)b * 16) * HW + p;
    unsigned short sv[16];
    #pragma unroll
    for (int j = 0; j < 16; ++j) sv[j] = mh[(size_t)j * HW];
    // (c) counts (uniform -> scalar loads)
    int start, cnt;
    cell_range(counts, b, start, cnt);

    // detect resolves while (b) is still in flight
    unsigned ow = o0 | o1 | o2 | o3;
    #pragma unroll
    for (int d = 1; d < 64; d <<= 1) ow |= __shfl_xor(ow, d, 64);
    const unsigned or0 = ow & 0xFFu, or1 = (ow >> 8) & 0xFFu;
    int msize;
    if (or1 == 0)                        msize = 4;  // int32/f32 masks
    else if (or0 == 0x80 || or0 == 0x00) msize = 2;  // bf16 (3F80) / f16 (3C00)
    else                                 msize = 1;  // bool/uint8

    unsigned w = 0;
    if (msize == 2 && start == b * 16 && cnt == 16) {
        // fast path: consume speculative loads (always taken in practice)
        #pragma unroll
        for (int j = 0; j < 16; ++j) w |= (sv[j] ? 1u : 0u) << j;
    } else if (msize == 2) {
        const unsigned short* m2 = (const unsigned short*)maskv + (size_t)start * HW + p;
        for (int j = 0; j < cnt; ++j) w |= (m2[(size_t)j * HW] ? 1u : 0u) << j;
    } else if (msize == 4) {
        const unsigned* m4 = (const unsigned*)maskv + (size_t)start * HW + p;
        for (int j = 0; j < cnt; ++j) w |= (m4[(size_t)j * HW] ? 1u : 0u) << j;
    } else {
        const unsigned char* m1 = (const unsigned char*)maskv + (size_t)start * HW + p;
        for (int j = 0; j < cnt; ++j) w |= (m1[(size_t)j * HW] ? 1u : 0u) << j;
    }
    packed[idx] = (unsigned short)w;
}

// ---- kernel 2: one 256-thr block per (b, c). grid (256, 8) ----
__global__ __launch_bounds__(256, 8)
void roipool_main(const void* __restrict__ featv,
                  const unsigned short* __restrict__ packed,
                  const int* __restrict__ counts,
                  void* __restrict__ outv) {
    const int c   = blockIdx.x;
    const int b   = blockIdx.y;
    const int tid = threadIdx.x;
    const int l   = tid & 63;      // lane
    const int wv  = tid >> 6;      // wave 0..3
    const float NEG = -__builtin_inff();
    const unsigned NEGI = 0xFF800000u;   // f32 -inf bits

    const int p0 = tid * 16;   // this thread's 16 pixels

    // --- loads issued up front; DETECT FIRST so its waitcnt drains first ---
    const unsigned w0 = ((const unsigned*)featv)[l];          // detect dword
    uint4 pa = *(const uint4*)(packed + ((size_t)b << 12) + p0);
    uint4 pb = *(const uint4*)(packed + ((size_t)b << 12) + p0 + 8);
    // speculative bf16-interp feature loads (in-bounds for f32 data too:
    // bf16 interp touches only the first half of an f32 buffer)
    const unsigned short* fp16 = (const unsigned short*)featv
                               + (((size_t)(b * CCH + c)) << 12) + p0;
    uint4 f0 = *(const uint4*)(fp16);
    uint4 f1 = *(const uint4*)(fp16 + 8);
    // counts (uniform -> scalar loads; gates only the final store)
    int start, cnt;
    cell_range(counts, b, start, cnt);

    // ballot needs only w0 (oldest outstanding load) -> retires at vmcnt(4)
    const unsigned eb = (w0 >> 8) & 0x7F;
    const unsigned long long bm = __ballot(eb >= 0x3B && eb <= 0x41);
    const int fbf16 = (__popcll(bm) >= 48);

    const unsigned pmw[8] = {pa.x, pa.y, pa.z, pa.w, pb.x, pb.y, pb.z, pb.w};

    float vmax[16];
    #pragma unroll
    for (int j = 0; j < 16; ++j) vmax[j] = NEG;

    if (fbf16) {
        // hot path: fe/fo derived on the fly from raw dwords (no pe/po arrays)
        const unsigned w8[8] = {f0.x, f0.y, f0.z, f0.w, f1.x, f1.y, f1.z, f1.w};
        #pragma unroll
        for (int k = 0; k < 8; ++k) {
            const unsigned fe = w8[k] << 16;          // even px as f32 bits
            const unsigned fo = w8[k] & 0xFFFF0000u;  // odd px as f32 bits
            const unsigned mw = pmw[k];   // bits 0..15: px 2k; 16..31: px 2k+1
            #pragma unroll
            for (int j = 0; j < 16; ++j) {
                unsigned m0 = (unsigned)(((int)(mw << (31 - j))) >> 31);  // bfe
                unsigned m1 = (unsigned)(((int)(mw << (15 - j))) >> 31);
                float s0 = __uint_as_float((fe & m0) | (NEGI & ~m0));     // bfi
                float s1 = __uint_as_float((fo & m1) | (NEGI & ~m1));
                vmax[j] = fmaxf(fmaxf(vmax[j], s0), s1);                  // max3
            }
        }
    } else {
        // cold path (never taken for this harness): branch-local f32 reload
        const float* fp = (const float*)featv + (((size_t)(b * CCH + c)) << 12) + p0;
        #pragma unroll
        for (int q = 0; q < 4; ++q) {
            uint4 a = *(const uint4*)(fp + q * 4);    // px 4q..4q+3
            const unsigned fe2[2] = {a.x, a.z};
            const unsigned fo2[2] = {a.y, a.w};
            #pragma unroll
            for (int h = 0; h < 2; ++h) {
                const unsigned fe = fe2[h], fo = fo2[h];
                const unsigned mw = pmw[q * 2 + h];
                #pragma unroll
                for (int j = 0; j < 16; ++j) {
                    unsigned m0 = (unsigned)(((int)(mw << (31 - j))) >> 31);
                    unsigned m1 = (unsigned)(((int)(mw << (15 - j))) >> 31);
                    float s0 = __uint_as_float((fe & m0) | (NEGI & ~m0));
                    float s1 = __uint_as_float((fo & m1) | (NEGI & ~m1));
                    vmax[j] = fmaxf(fmaxf(vmax[j], s0), s1);
                }
            }
        }
    }

    // Fold-as-you-go butterfly (verified, R8/R9): each step halves the value
    // set; lane bit k picks which cell half stays. After 4 folds lane l holds
    // cell (l&15); d=16,32 merge the 4 duplicate groups. 17 swizzles total.
    float v8[8];
    {
        const bool s = (l & 1);
        #pragma unroll
        for (int j = 0; j < 8; ++j) {
            float snd = s ? vmax[2*j]   : vmax[2*j+1];
            float mne = s ? vmax[2*j+1] : vmax[2*j];
            v8[j] = fmaxf(mne, __shfl_xor(snd, 1, 64));   // cell 2j + (l&1)
        }
    }
    float v4[4];
    {
        const bool s = (l >> 1) & 1;
        #pragma unroll
        for (int j = 0; j < 4; ++j) {
            float snd = s ? v8[2*j]   : v8[2*j+1];
            float mne = s ? v8[2*j+1] : v8[2*j];
            v4[j] = fmaxf(mne, __shfl_xor(snd, 2, 64));   // cell 4j + (l&3)
        }
    }
    float v2[2];
    {
        const bool s = (l >> 2) & 1;
        #pragma unroll
        for (int j = 0; j < 2; ++j) {
            float snd = s ? v4[2*j]   : v4[2*j+1];
            float mne = s ? v4[2*j+1] : v4[2*j];
            v2[j] = fmaxf(mne, __shfl_xor(snd, 4, 64));   // cell 8j + (l&7)
        }
    }
    float v1;
    {
        const bool s = (l >> 3) & 1;
        float snd = s ? v2[0] : v2[1];
        float mne = s ? v2[1] : v2[0];
        v1 = fmaxf(mne, __shfl_xor(snd, 8, 64));          // cell = l & 15
    }
    v1 = fmaxf(v1, __shfl_xor(v1, 16, 64));
    v1 = fmaxf(v1, __shfl_xor(v1, 32, 64));

    // cross-wave combine: 4 waves x 16 cells, ONE barrier, 320 B LDS.
    __shared__ float red[4][16];
    if (l < 16) red[wv][l] = v1;
    __syncthreads();
    if (tid < 16) {
        float m = fmaxf(fmaxf(red[0][tid], red[1][tid]),
                        fmaxf(red[2][tid], red[3][tid]));
        if (tid < cnt) {
            const size_t oi = (size_t)(start + tid) * CCH + c;
            if (fbf16) ((__hip_bfloat16*)outv)[oi] = __float2bfloat16(m);
            else       ((float*)outv)[oi]          = m;
        }
    }
}

extern "C" void kernel_launch(void* const* d_in, const int* in_sizes, int n_in,
                              void* d_out, int out_size, void* d_ws, size_t ws_size,
                              hipStream_t stream) {
    const void* feat  = d_in[0];
    const void* masks = d_in[1];
    const int* counts = (const int*)d_in[2];
    unsigned short* packed = (unsigned short*)d_ws;   // 8*4096*2 = 64 KiB

    pack_masks<<<(BIMG * HW) / 256, 256, 0, stream>>>(masks, counts, packed);

    dim3 grid(CCH, BIMG);   // 2048 blocks, one per (b, c)
    roipool_main<<<grid, 256, 0, stream>>>(feat, packed, counts, d_out);
}

// Round 6
// 269.640 us; speedup vs baseline: 1.1943x; 1.1943x over previous
//
#include <hip/hip_runtime.h>
#include <hip/hip_bf16.h>

// RoIPool max over boolean cell masks (harness bf16-ifies floats AND bools).
// B=8, C=256, H=W=64 (HW=4096), N=128 cells (16/image).
// R11 (post-mortem R10: __launch_bounds__(256,8) pushed the allocator to the
// 32-VGPR tier -> ~1KB/thread scratch spill, 546MB writes, 254us. The (256,8)
// constraint is fragile on this body — vmax16+w8+pmw8 alone is 32 regs.
// Also confirmed: harness floor ~= 68us (43 fill + 25 reset train); our
// kernels are the remaining ~18us, ideal ~8us.
// Fix: keep R10's lean body (no pe/po arrays = smallest live set; detect
// dword issued first; 17-swizzle fold-butterfly) but restore the PROVEN
// (256,4) bound (R5/R7: 128-VGPR cap, zero spill). Single-variable change.)

#define HW    4096
#define BIMG  8
#define CCH   256
#define NCELL 128

__device__ __forceinline__ void cell_range(const int* counts, int b, int& start, int& cnt) {
    start = 0;
    for (int i = 0; i < b; ++i) start += counts[i];
    if (start > NCELL) start = NCELL;
    cnt = counts[b];
    // jnp.repeat(..., total_repeat_length=N) pads with the last value:
    if (b == BIMG - 1 && start + cnt < NCELL) cnt = NCELL - start;
    if (cnt > 16) cnt = 16;
    if (start + cnt > NCELL) cnt = NCELL - start;
    if (cnt < 0) cnt = 0;
}

// ---- kernel 1: bit-pack masks. grid 128 x 256 threads = 32768 = BIMG*HW ----
__global__ __launch_bounds__(256)
void pack_masks(const void* __restrict__ maskv,
                const int* __restrict__ counts,
                unsigned short* __restrict__ packed) {
    const int tid = threadIdx.x;
    const int l   = tid & 63;
    const int idx = blockIdx.x * 256 + tid;      // b*HW + p
    const int b = idx >> 12;
    const int p = idx & (HW - 1);

    // --- ALL loads issued up front, independent; detect dwords first ---
    // (a) dtype detect: byte-lane OR over first 1 KiB (proven R3..R9)
    const unsigned* mw0 = (const unsigned*)maskv;
    const unsigned o0 = mw0[l * 4], o1 = mw0[l * 4 + 1],
                   o2 = mw0[l * 4 + 2], o3 = mw0[l * 4 + 3];
    // (b) speculative bf16-interp mask loads assuming start=b*16, cnt=16
    //     (actual harness layout; bf16 interp never exceeds the real buffer)
    const unsigned short* mh = (const unsigned short*)maskv + ((size_t)b * 16) * HW + p;
    unsigned short sv[16];
    #pragma unroll
    for (int j = 0; j < 16; ++j) sv[j] = mh[(size_t)j * HW];
    // (c) counts (uniform -> scalar loads)
    int start, cnt;
    cell_range(counts, b, start, cnt);

    // detect resolves while (b) is still in flight
    unsigned ow = o0 | o1 | o2 | o3;
    #pragma unroll
    for (int d = 1; d < 64; d <<= 1) ow |= __shfl_xor(ow, d, 64);
    const unsigned or0 = ow & 0xFFu, or1 = (ow >> 8) & 0xFFu;
    int msize;
    if (or1 == 0)                        msize = 4;  // int32/f32 masks
    else if (or0 == 0x80 || or0 == 0x00) msize = 2;  // bf16 (3F80) / f16 (3C00)
    else                                 msize = 1;  // bool/uint8

    unsigned w = 0;
    if (msize == 2 && start == b * 16 && cnt == 16) {
        // fast path: consume speculative loads (always taken in practice)
        #pragma unroll
        for (int j = 0; j < 16; ++j) w |= (sv[j] ? 1u : 0u) << j;
    } else if (msize == 2) {
        const unsigned short* m2 = (const unsigned short*)maskv + (size_t)start * HW + p;
        for (int j = 0; j < cnt; ++j) w |= (m2[(size_t)j * HW] ? 1u : 0u) << j;
    } else if (msize == 4) {
        const unsigned* m4 = (const unsigned*)maskv + (size_t)start * HW + p;
        for (int j = 0; j < cnt; ++j) w |= (m4[(size_t)j * HW] ? 1u : 0u) << j;
    } else {
        const unsigned char* m1 = (const unsigned char*)maskv + (size_t)start * HW + p;
        for (int j = 0; j < cnt; ++j) w |= (m1[(size_t)j * HW] ? 1u : 0u) << j;
    }
    packed[idx] = (unsigned short)w;
}

// ---- kernel 2: one 256-thr block per (b, c). grid (256, 8) ----
// (256,4): proven-stable bound (R5/R7) — 128-VGPR cap, zero spill; actual
// occupancy self-selects higher if the natural allocation lands <=64.
__global__ __launch_bounds__(256, 4)
void roipool_main(const void* __restrict__ featv,
                  const unsigned short* __restrict__ packed,
                  const int* __restrict__ counts,
                  void* __restrict__ outv) {
    const int c   = blockIdx.x;
    const int b   = blockIdx.y;
    const int tid = threadIdx.x;
    const int l   = tid & 63;      // lane
    const int wv  = tid >> 6;      // wave 0..3
    const float NEG = -__builtin_inff();
    const unsigned NEGI = 0xFF800000u;   // f32 -inf bits

    const int p0 = tid * 16;   // this thread's 16 pixels

    // --- loads issued up front; DETECT FIRST so its waitcnt drains first ---
    const unsigned w0 = ((const unsigned*)featv)[l];          // detect dword
    uint4 pa = *(const uint4*)(packed + ((size_t)b << 12) + p0);
    uint4 pb = *(const uint4*)(packed + ((size_t)b << 12) + p0 + 8);
    // speculative bf16-interp feature loads (in-bounds for f32 data too:
    // bf16 interp touches only the first half of an f32 buffer)
    const unsigned short* fp16 = (const unsigned short*)featv
                               + (((size_t)(b * CCH + c)) << 12) + p0;
    uint4 f0 = *(const uint4*)(fp16);
    uint4 f1 = *(const uint4*)(fp16 + 8);
    // counts (uniform -> scalar loads; gates only the final store)
    int start, cnt;
    cell_range(counts, b, start, cnt);

    // ballot needs only w0 (oldest outstanding load) -> retires at vmcnt(4)
    const unsigned eb = (w0 >> 8) & 0x7F;
    const unsigned long long bm = __ballot(eb >= 0x3B && eb <= 0x41);
    const int fbf16 = (__popcll(bm) >= 48);

    const unsigned pmw[8] = {pa.x, pa.y, pa.z, pa.w, pb.x, pb.y, pb.z, pb.w};

    float vmax[16];
    #pragma unroll
    for (int j = 0; j < 16; ++j) vmax[j] = NEG;

    if (fbf16) {
        // hot path: fe/fo derived on the fly from raw dwords (no pe/po arrays)
        const unsigned w8[8] = {f0.x, f0.y, f0.z, f0.w, f1.x, f1.y, f1.z, f1.w};
        #pragma unroll
        for (int k = 0; k < 8; ++k) {
            const unsigned fe = w8[k] << 16;          // even px as f32 bits
            const unsigned fo = w8[k] & 0xFFFF0000u;  // odd px as f32 bits
            const unsigned mw = pmw[k];   // bits 0..15: px 2k; 16..31: px 2k+1
            #pragma unroll
            for (int j = 0; j < 16; ++j) {
                unsigned m0 = (unsigned)(((int)(mw << (31 - j))) >> 31);  // bfe
                unsigned m1 = (unsigned)(((int)(mw << (15 - j))) >> 31);
                float s0 = __uint_as_float((fe & m0) | (NEGI & ~m0));     // bfi
                float s1 = __uint_as_float((fo & m1) | (NEGI & ~m1));
                vmax[j] = fmaxf(fmaxf(vmax[j], s0), s1);                  // max3
            }
        }
    } else {
        // cold path (never taken for this harness): branch-local f32 reload
        const float* fp = (const float*)featv + (((size_t)(b * CCH + c)) << 12) + p0;
        #pragma unroll
        for (int q = 0; q < 4; ++q) {
            uint4 a = *(const uint4*)(fp + q * 4);    // px 4q..4q+3
            const unsigned fe2[2] = {a.x, a.z};
            const unsigned fo2[2] = {a.y, a.w};
            #pragma unroll
            for (int h = 0; h < 2; ++h) {
                const unsigned fe = fe2[h], fo = fo2[h];
                const unsigned mw = pmw[q * 2 + h];
                #pragma unroll
                for (int j = 0; j < 16; ++j) {
                    unsigned m0 = (unsigned)(((int)(mw << (31 - j))) >> 31);
                    unsigned m1 = (unsigned)(((int)(mw << (15 - j))) >> 31);
                    float s0 = __uint_as_float((fe & m0) | (NEGI & ~m0));
                    float s1 = __uint_as_float((fo & m1) | (NEGI & ~m1));
                    vmax[j] = fmaxf(fmaxf(vmax[j], s0), s1);
                }
            }
        }
    }

    // Fold-as-you-go butterfly (verified, R8..R10): each step halves the value
    // set; lane bit k picks which cell half stays. After 4 folds lane l holds
    // cell (l&15); d=16,32 merge the 4 duplicate groups. 17 swizzles total.
    float v8[8];
    {
        const bool s = (l & 1);
        #pragma unroll
        for (int j = 0; j < 8; ++j) {
            float snd = s ? vmax[2*j]   : vmax[2*j+1];
            float mne = s ? vmax[2*j+1] : vmax[2*j];
            v8[j] = fmaxf(mne, __shfl_xor(snd, 1, 64));   // cell 2j + (l&1)
        }
    }
    float v4[4];
    {
        const bool s = (l >> 1) & 1;
        #pragma unroll
        for (int j = 0; j < 4; ++j) {
            float snd = s ? v8[2*j]   : v8[2*j+1];
            float mne = s ? v8[2*j+1] : v8[2*j];
            v4[j] = fmaxf(mne, __shfl_xor(snd, 2, 64));   // cell 4j + (l&3)
        }
    }
    float v2[2];
    {
        const bool s = (l >> 2) & 1;
        #pragma unroll
        for (int j = 0; j < 2; ++j) {
            float snd = s ? v4[2*j]   : v4[2*j+1];
            float mne = s ? v4[2*j+1] : v4[2*j];
            v2[j] = fmaxf(mne, __shfl_xor(snd, 4, 64));   // cell 8j + (l&7)
        }
    }
    float v1;
    {
        const bool s = (l >> 3) & 1;
        float snd = s ? v2[0] : v2[1];
        float mne = s ? v2[1] : v2[0];
        v1 = fmaxf(mne, __shfl_xor(snd, 8, 64));          // cell = l & 15
    }
    v1 = fmaxf(v1, __shfl_xor(v1, 16, 64));
    v1 = fmaxf(v1, __shfl_xor(v1, 32, 64));

    // cross-wave combine: 4 waves x 16 cells, ONE barrier, 320 B LDS.
    __shared__ float red[4][16];
    if (l < 16) red[wv][l] = v1;
    __syncthreads();
    if (tid < 16) {
        float m = fmaxf(fmaxf(red[0][tid], red[1][tid]),
                        fmaxf(red[2][tid], red[3][tid]));
        if (tid < cnt) {
            const size_t oi = (size_t)(start + tid) * CCH + c;
            if (fbf16) ((__hip_bfloat16*)outv)[oi] = __float2bfloat16(m);
            else       ((float*)outv)[oi]          = m;
        }
    }
}

extern "C" void kernel_launch(void* const* d_in, const int* in_sizes, int n_in,
                              void* d_out, int out_size, void* d_ws, size_t ws_size,
                              hipStream_t stream) {
    const void* feat  = d_in[0];
    const void* masks = d_in[1];
    const int* counts = (const int*)d_in[2];
    unsigned short* packed = (unsigned short*)d_ws;   // 8*4096*2 = 64 KiB

    pack_masks<<<(BIMG * HW) / 256, 256, 0, stream>>>(masks, counts, packed);

    dim3 grid(CCH, BIMG);   // 2048 blocks, one per (b, c)
    roipool_main<<<grid, 256, 0, stream>>>(feat, packed, counts, d_out);
}

// Round 7
// 264.463 us; speedup vs baseline: 1.2177x; 1.0196x over previous
//
#include <hip/hip_runtime.h>
#include <hip/hip_bf16.h>

// RoIPool max over boolean cell masks (harness bf16-ifies floats AND bools).
// B=8, C=256, H=W=64 (HW=4096), N=128 cells (16/image).
// R12 (post-mortem R11: with (256,4) the allocator CHOSE 64 VGPR and spilled
// ~1KB/thread (WRITE 505MB, 200us). Root cause: __launch_bounds__ 2nd arg
// sets only MIN waves/EU; LLVM then opportunistically targets HIGHER
// occupancy and squeezed the lean body into the 64-reg tier on a bad
// spill-cost estimate (R10: same squeeze to 32). R5/R7's fatter body
// exceeded the squeeze threshold -> clean 128. The lean body invites it.
// Fix: pin min=max via amdgpu_waves_per_eu(4,4) -> allocator has no
// incentive to shrink below the 128-VGPR budget; ~55 live regs, no spill.
// Everything else byte-identical to R11.)

#define HW    4096
#define BIMG  8
#define CCH   256
#define NCELL 128

__device__ __forceinline__ void cell_range(const int* counts, int b, int& start, int& cnt) {
    start = 0;
    for (int i = 0; i < b; ++i) start += counts[i];
    if (start > NCELL) start = NCELL;
    cnt = counts[b];
    // jnp.repeat(..., total_repeat_length=N) pads with the last value:
    if (b == BIMG - 1 && start + cnt < NCELL) cnt = NCELL - start;
    if (cnt > 16) cnt = 16;
    if (start + cnt > NCELL) cnt = NCELL - start;
    if (cnt < 0) cnt = 0;
}

// ---- kernel 1: bit-pack masks. grid 128 x 256 threads = 32768 = BIMG*HW ----
__global__ __launch_bounds__(256)
void pack_masks(const void* __restrict__ maskv,
                const int* __restrict__ counts,
                unsigned short* __restrict__ packed) {
    const int tid = threadIdx.x;
    const int l   = tid & 63;
    const int idx = blockIdx.x * 256 + tid;      // b*HW + p
    const int b = idx >> 12;
    const int p = idx & (HW - 1);

    // --- ALL loads issued up front, independent; detect dwords first ---
    // (a) dtype detect: byte-lane OR over first 1 KiB (proven R3..R11)
    const unsigned* mw0 = (const unsigned*)maskv;
    const unsigned o0 = mw0[l * 4], o1 = mw0[l * 4 + 1],
                   o2 = mw0[l * 4 + 2], o3 = mw0[l * 4 + 3];
    // (b) speculative bf16-interp mask loads assuming start=b*16, cnt=16
    //     (actual harness layout; bf16 interp never exceeds the real buffer)
    const unsigned short* mh = (const unsigned short*)maskv + ((size_t)b * 16) * HW + p;
    unsigned short sv[16];
    #pragma unroll
    for (int j = 0; j < 16; ++j) sv[j] = mh[(size_t)j * HW];
    // (c) counts (uniform -> scalar loads)
    int start, cnt;
    cell_range(counts, b, start, cnt);

    // detect resolves while (b) is still in flight
    unsigned ow = o0 | o1 | o2 | o3;
    #pragma unroll
    for (int d = 1; d < 64; d <<= 1) ow |= __shfl_xor(ow, d, 64);
    const unsigned or0 = ow & 0xFFu, or1 = (ow >> 8) & 0xFFu;
    int msize;
    if (or1 == 0)                        msize = 4;  // int32/f32 masks
    else if (or0 == 0x80 || or0 == 0x00) msize = 2;  // bf16 (3F80) / f16 (3C00)
    else                                 msize = 1;  // bool/uint8

    unsigned w = 0;
    if (msize == 2 && start == b * 16 && cnt == 16) {
        // fast path: consume speculative loads (always taken in practice)
        #pragma unroll
        for (int j = 0; j < 16; ++j) w |= (sv[j] ? 1u : 0u) << j;
    } else if (msize == 2) {
        const unsigned short* m2 = (const unsigned short*)maskv + (size_t)start * HW + p;
        for (int j = 0; j < cnt; ++j) w |= (m2[(size_t)j * HW] ? 1u : 0u) << j;
    } else if (msize == 4) {
        const unsigned* m4 = (const unsigned*)maskv + (size_t)start * HW + p;
        for (int j = 0; j < cnt; ++j) w |= (m4[(size_t)j * HW] ? 1u : 0u) << j;
    } else {
        const unsigned char* m1 = (const unsigned char*)maskv + (size_t)start * HW + p;
        for (int j = 0; j < cnt; ++j) w |= (m1[(size_t)j * HW] ? 1u : 0u) << j;
    }
    packed[idx] = (unsigned short)w;
}

// ---- kernel 2: one 256-thr block per (b, c). grid (256, 8) ----
// amdgpu_waves_per_eu(4,4): pins the allocator's occupancy target to exactly
// 4 waves/EU (128-VGPR budget). min=max forbids the opportunistic squeeze to
// the 64/32-reg tiers that caused R10/R11's 0.5-1KB/thread scratch spill.
__global__ __launch_bounds__(256)
__attribute__((amdgpu_waves_per_eu(4, 4)))
void roipool_main(const void* __restrict__ featv,
                  const unsigned short* __restrict__ packed,
                  const int* __restrict__ counts,
                  void* __restrict__ outv) {
    const int c   = blockIdx.x;
    const int b   = blockIdx.y;
    const int tid = threadIdx.x;
    const int l   = tid & 63;      // lane
    const int wv  = tid >> 6;      // wave 0..3
    const float NEG = -__builtin_inff();
    const unsigned NEGI = 0xFF800000u;   // f32 -inf bits

    const int p0 = tid * 16;   // this thread's 16 pixels

    // --- loads issued up front; DETECT FIRST so its waitcnt drains first ---
    const unsigned w0 = ((const unsigned*)featv)[l];          // detect dword
    uint4 pa = *(const uint4*)(packed + ((size_t)b << 12) + p0);
    uint4 pb = *(const uint4*)(packed + ((size_t)b << 12) + p0 + 8);
    // speculative bf16-interp feature loads (in-bounds for f32 data too:
    // bf16 interp touches only the first half of an f32 buffer)
    const unsigned short* fp16 = (const unsigned short*)featv
                               + (((size_t)(b * CCH + c)) << 12) + p0;
    uint4 f0 = *(const uint4*)(fp16);
    uint4 f1 = *(const uint4*)(fp16 + 8);
    // counts (uniform -> scalar loads; gates only the final store)
    int start, cnt;
    cell_range(counts, b, start, cnt);

    // ballot needs only w0 (oldest outstanding load) -> retires at vmcnt(4)
    const unsigned eb = (w0 >> 8) & 0x7F;
    const unsigned long long bm = __ballot(eb >= 0x3B && eb <= 0x41);
    const int fbf16 = (__popcll(bm) >= 48);

    const unsigned pmw[8] = {pa.x, pa.y, pa.z, pa.w, pb.x, pb.y, pb.z, pb.w};

    float vmax[16];
    #pragma unroll
    for (int j = 0; j < 16; ++j) vmax[j] = NEG;

    if (fbf16) {
        // hot path: fe/fo derived on the fly from raw dwords (no pe/po arrays)
        const unsigned w8[8] = {f0.x, f0.y, f0.z, f0.w, f1.x, f1.y, f1.z, f1.w};
        #pragma unroll
        for (int k = 0; k < 8; ++k) {
            const unsigned fe = w8[k] << 16;          // even px as f32 bits
            const unsigned fo = w8[k] & 0xFFFF0000u;  // odd px as f32 bits
            const unsigned mw = pmw[k];   // bits 0..15: px 2k; 16..31: px 2k+1
            #pragma unroll
            for (int j = 0; j < 16; ++j) {
                unsigned m0 = (unsigned)(((int)(mw << (31 - j))) >> 31);  // bfe
                unsigned m1 = (unsigned)(((int)(mw << (15 - j))) >> 31);
                float s0 = __uint_as_float((fe & m0) | (NEGI & ~m0));     // bfi
                float s1 = __uint_as_float((fo & m1) | (NEGI & ~m1));
                vmax[j] = fmaxf(fmaxf(vmax[j], s0), s1);                  // max3
            }
        }
    } else {
        // cold path (never taken for this harness): branch-local f32 reload
        const float* fp = (const float*)featv + (((size_t)(b * CCH + c)) << 12) + p0;
        #pragma unroll
        for (int q = 0; q < 4; ++q) {
            uint4 a = *(const uint4*)(fp + q * 4);    // px 4q..4q+3
            const unsigned fe2[2] = {a.x, a.z};
            const unsigned fo2[2] = {a.y, a.w};
            #pragma unroll
            for (int h = 0; h < 2; ++h) {
                const unsigned fe = fe2[h], fo = fo2[h];
                const unsigned mw = pmw[q * 2 + h];
                #pragma unroll
                for (int j = 0; j < 16; ++j) {
                    unsigned m0 = (unsigned)(((int)(mw << (31 - j))) >> 31);
                    unsigned m1 = (unsigned)(((int)(mw << (15 - j))) >> 31);
                    float s0 = __uint_as_float((fe & m0) | (NEGI & ~m0));
                    float s1 = __uint_as_float((fo & m1) | (NEGI & ~m1));
                    vmax[j] = fmaxf(fmaxf(vmax[j], s0), s1);
                }
            }
        }
    }

    // Fold-as-you-go butterfly (verified, R8..R11): each step halves the value
    // set; lane bit k picks which cell half stays. After 4 folds lane l holds
    // cell (l&15); d=16,32 merge the 4 duplicate groups. 17 swizzles total.
    float v8[8];
    {
        const bool s = (l & 1);
        #pragma unroll
        for (int j = 0; j < 8; ++j) {
            float snd = s ? vmax[2*j]   : vmax[2*j+1];
            float mne = s ? vmax[2*j+1] : vmax[2*j];
            v8[j] = fmaxf(mne, __shfl_xor(snd, 1, 64));   // cell 2j + (l&1)
        }
    }
    float v4[4];
    {
        const bool s = (l >> 1) & 1;
        #pragma unroll
        for (int j = 0; j < 4; ++j) {
            float snd = s ? v8[2*j]   : v8[2*j+1];
            float mne = s ? v8[2*j+1] : v8[2*j];
            v4[j] = fmaxf(mne, __shfl_xor(snd, 2, 64));   // cell 4j + (l&3)
        }
    }
    float v2[2];
    {
        const bool s = (l >> 2) & 1;
        #pragma unroll
        for (int j = 0; j < 2; ++j) {
            float snd = s ? v4[2*j]   : v4[2*j+1];
            float mne = s ? v4[2*j+1] : v4[2*j];
            v2[j] = fmaxf(mne, __shfl_xor(snd, 4, 64));   // cell 8j + (l&7)
        }
    }
    float v1;
    {
        const bool s = (l >> 3) & 1;
        float snd = s ? v2[0] : v2[1];
        float mne = s ? v2[1] : v2[0];
        v1 = fmaxf(mne, __shfl_xor(snd, 8, 64));          // cell = l & 15
    }
    v1 = fmaxf(v1, __shfl_xor(v1, 16, 64));
    v1 = fmaxf(v1, __shfl_xor(v1, 32, 64));

    // cross-wave combine: 4 waves x 16 cells, ONE barrier, 320 B LDS.
    __shared__ float red[4][16];
    if (l < 16) red[wv][l] = v1;
    __syncthreads();
    if (tid < 16) {
        float m = fmaxf(fmaxf(red[0][tid], red[1][tid]),
                        fmaxf(red[2][tid], red[3][tid]));
        if (tid < cnt) {
            const size_t oi = (size_t)(start + tid) * CCH + c;
            if (fbf16) ((__hip_bfloat16*)outv)[oi] = __float2bfloat16(m);
            else       ((float*)outv)[oi]          = m;
        }
    }
}

extern "C" void kernel_launch(void* const* d_in, const int* in_sizes, int n_in,
                              void* d_out, int out_size, void* d_ws, size_t ws_size,
                              hipStream_t stream) {
    const void* feat  = d_in[0];
    const void* masks = d_in[1];
    const int* counts = (const int*)d_in[2];
    unsigned short* packed = (unsigned short*)d_ws;   // 8*4096*2 = 64 KiB

    pack_masks<<<(BIMG * HW) / 256, 256, 0, stream>>>(masks, counts, packed);

    dim3 grid(CCH, BIMG);   // 2048 blocks, one per (b, c)
    roipool_main<<<grid, 256, 0, stream>>>(feat, packed, counts, d_out);
}

// Round 8
// 89.831 us; speedup vs baseline: 3.5848x; 2.9440x over previous
//
#include <hip/hip_runtime.h>
#include <hip/hip_bf16.h>

// RoIPool max over boolean cell masks (harness bf16-ifies floats AND bools).
// B=8, C=256, H=W=64 (HW=4096), N=128 cells (16/image).
// R13 (post-mortem R12: waves_per_eu(4,4) raised the budget to 128 VGPR yet
// the allocation STAYED 64 + 505MB spill -> the spill is NOT an occupancy
// choice. Consistent explanation: private arrays (vmax[16]/pmw[8]/w8[8])
// left in scratch (PromoteAlloca gives up on this body) and/or pre-RA
// scheduler ballooning the flattened 8x16 loop. Occupancy knobs can't fix
// an un-promoted alloca -> change the code shape):
//   1. ZERO private arrays: all state in named scalars via macros (x0..x15,
//      e0..e7/o0..o7). Named scalars are SSA -- no alloca exists to demote.
//   2. sched_barrier(0) after each k-group: caps live-range ballooning
//      (per group only fe/fo/mw + 16 accumulators live). Pure-VALU region,
//      so pinning is free (m141's caveat applies to load/MFMA pipelines).
//   3. Plain __launch_bounds__(256); no occupancy attributes (R12: not the
//      lever, adds SGPR/dispatch weirdness).
//   Proven parts kept verbatim: R9 pack_masks, detect-first speculative
//   loads, fold-butterfly (named-scalar form), 1 barrier + 320B LDS combine.

#define HW    4096
#define BIMG  8
#define CCH   256
#define NCELL 128

__device__ __forceinline__ void cell_range(const int* counts, int b, int& start, int& cnt) {
    start = 0;
    for (int i = 0; i < b; ++i) start += counts[i];
    if (start > NCELL) start = NCELL;
    cnt = counts[b];
    // jnp.repeat(..., total_repeat_length=N) pads with the last value:
    if (b == BIMG - 1 && start + cnt < NCELL) cnt = NCELL - start;
    if (cnt > 16) cnt = 16;
    if (start + cnt > NCELL) cnt = NCELL - start;
    if (cnt < 0) cnt = 0;
}

// ---- kernel 1: bit-pack masks. grid 128 x 256 threads = 32768 = BIMG*HW ----
__global__ __launch_bounds__(256)
void pack_masks(const void* __restrict__ maskv,
                const int* __restrict__ counts,
                unsigned short* __restrict__ packed) {
    const int tid = threadIdx.x;
    const int l   = tid & 63;
    const int idx = blockIdx.x * 256 + tid;      // b*HW + p
    const int b = idx >> 12;
    const int p = idx & (HW - 1);

    // --- ALL loads issued up front, independent; detect dwords first ---
    // (a) dtype detect: byte-lane OR over first 1 KiB (proven R3..R12)
    const unsigned* mw0 = (const unsigned*)maskv;
    const unsigned d0 = mw0[l * 4], d1 = mw0[l * 4 + 1],
                   d2 = mw0[l * 4 + 2], d3 = mw0[l * 4 + 3];
    // (b) speculative bf16-interp mask loads assuming start=b*16, cnt=16
    //     (actual harness layout; bf16 interp never exceeds the real buffer)
    const unsigned short* mh = (const unsigned short*)maskv + ((size_t)b * 16) * HW + p;
    unsigned short sv[16];
    #pragma unroll
    for (int j = 0; j < 16; ++j) sv[j] = mh[(size_t)j * HW];
    // (c) counts (uniform -> scalar loads)
    int start, cnt;
    cell_range(counts, b, start, cnt);

    // detect resolves while (b) is still in flight
    unsigned ow = d0 | d1 | d2 | d3;
    #pragma unroll
    for (int d = 1; d < 64; d <<= 1) ow |= __shfl_xor(ow, d, 64);
    const unsigned or0 = ow & 0xFFu, or1 = (ow >> 8) & 0xFFu;
    int msize;
    if (or1 == 0)                        msize = 4;  // int32/f32 masks
    else if (or0 == 0x80 || or0 == 0x00) msize = 2;  // bf16 (3F80) / f16 (3C00)
    else                                 msize = 1;  // bool/uint8

    unsigned w = 0;
    if (msize == 2 && start == b * 16 && cnt == 16) {
        // fast path: consume speculative loads (always taken in practice)
        #pragma unroll
        for (int j = 0; j < 16; ++j) w |= (sv[j] ? 1u : 0u) << j;
    } else if (msize == 2) {
        const unsigned short* m2 = (const unsigned short*)maskv + (size_t)start * HW + p;
        for (int j = 0; j < cnt; ++j) w |= (m2[(size_t)j * HW] ? 1u : 0u) << j;
    } else if (msize == 4) {
        const unsigned* m4 = (const unsigned*)maskv + (size_t)start * HW + p;
        for (int j = 0; j < cnt; ++j) w |= (m4[(size_t)j * HW] ? 1u : 0u) << j;
    } else {
        const unsigned char* m1 = (const unsigned char*)maskv + (size_t)start * HW + p;
        for (int j = 0; j < cnt; ++j) w |= (m1[(size_t)j * HW] ? 1u : 0u) << j;
    }
    packed[idx] = (unsigned short)w;
}

// one masked-select + accumulate step for cell bit `j` of px pair (even,odd)
#define STEP(vm, j) {                                                     \
    unsigned m0_ = (unsigned)(((int)(mw << (31 - (j)))) >> 31);           \
    unsigned m1_ = (unsigned)(((int)(mw << (15 - (j)))) >> 31);           \
    float s0_ = __uint_as_float((fe & m0_) | (NEGI & ~m0_));              \
    float s1_ = __uint_as_float((fo & m1_) | (NEGI & ~m1_));              \
    vm = fmaxf(fmaxf(vm, s0_), s1_); }

// one px-pair group: feature even/odd dwords + mask dword, all 16 cells
#define KITER(fe_, fo_, mw_) {                                            \
    const unsigned fe = (fe_), fo = (fo_), mw = (mw_);                    \
    STEP(x0, 0)  STEP(x1, 1)  STEP(x2, 2)   STEP(x3, 3)                   \
    STEP(x4, 4)  STEP(x5, 5)  STEP(x6, 6)   STEP(x7, 7)                   \
    STEP(x8, 8)  STEP(x9, 9)  STEP(x10,10)  STEP(x11,11)                  \
    STEP(x12,12) STEP(x13,13) STEP(x14,14)  STEP(x15,15) }

// one fold-butterfly step: keep `ea` or `ob` depending on lane bit `sel`
#define FOLD(dst, ea, ob, sel, dist) {                                    \
    float snd_ = (sel) ? (ea) : (ob);                                     \
    float mne_ = (sel) ? (ob) : (ea);                                     \
    dst = fmaxf(mne_, __shfl_xor(snd_, (dist), 64)); }

// ---- kernel 2: one 256-thr block per (b, c). grid (256, 8) ----
__global__ __launch_bounds__(256)
void roipool_main(const void* __restrict__ featv,
                  const unsigned short* __restrict__ packed,
                  const int* __restrict__ counts,
                  void* __restrict__ outv) {
    const int c   = blockIdx.x;
    const int b   = blockIdx.y;
    const int tid = threadIdx.x;
    const int l   = tid & 63;      // lane
    const int wv  = tid >> 6;      // wave 0..3
    const float NEG = -__builtin_inff();
    const unsigned NEGI = 0xFF800000u;   // f32 -inf bits

    const int p0 = tid * 16;   // this thread's 16 pixels

    // --- loads issued up front; DETECT FIRST so its waitcnt drains first ---
    const unsigned w0 = ((const unsigned*)featv)[l];          // detect dword
    uint4 pa = *(const uint4*)(packed + ((size_t)b << 12) + p0);
    uint4 pb = *(const uint4*)(packed + ((size_t)b << 12) + p0 + 8);
    // speculative bf16-interp feature loads (in-bounds for f32 data too:
    // bf16 interp touches only the first half of an f32 buffer)
    const unsigned short* fp16 = (const unsigned short*)featv
                               + (((size_t)(b * CCH + c)) << 12) + p0;
    uint4 f0 = *(const uint4*)(fp16);
    uint4 f1 = *(const uint4*)(fp16 + 8);
    // counts (uniform -> scalar loads; gates only the final store)
    int start, cnt;
    cell_range(counts, b, start, cnt);

    // ballot needs only w0 (oldest outstanding load) -> retires early
    const unsigned eb = (w0 >> 8) & 0x7F;
    const unsigned long long bm = __ballot(eb >= 0x3B && eb <= 0x41);
    const int fbf16 = (__popcll(bm) >= 48);

    // feature even/odd px as f32 bit patterns -- NAMED scalars, no arrays
    unsigned e0,e1,e2,e3,e4,e5,e6,e7, o0,o1,o2,o3,o4,o5,o6,o7;
    if (fbf16) {
        e0 = f0.x << 16; o0 = f0.x & 0xFFFF0000u;
        e1 = f0.y << 16; o1 = f0.y & 0xFFFF0000u;
        e2 = f0.z << 16; o2 = f0.z & 0xFFFF0000u;
        e3 = f0.w << 16; o3 = f0.w & 0xFFFF0000u;
        e4 = f1.x << 16; o4 = f1.x & 0xFFFF0000u;
        e5 = f1.y << 16; o5 = f1.y & 0xFFFF0000u;
        e6 = f1.z << 16; o6 = f1.z & 0xFFFF0000u;
        e7 = f1.w << 16; o7 = f1.w & 0xFFFF0000u;
    } else {
        // cold path (never taken for this harness): reload as f32
        const float* fp = (const float*)featv + (((size_t)(b * CCH + c)) << 12) + p0;
        uint4 a0 = *(const uint4*)(fp);
        uint4 a1 = *(const uint4*)(fp + 4);
        uint4 a2 = *(const uint4*)(fp + 8);
        uint4 a3 = *(const uint4*)(fp + 12);
        e0 = a0.x; o0 = a0.y;  e1 = a0.z; o1 = a0.w;
        e2 = a1.x; o2 = a1.y;  e3 = a1.z; o3 = a1.w;
        e4 = a2.x; o4 = a2.y;  e5 = a2.z; o5 = a2.w;
        e6 = a3.x; o6 = a3.y;  e7 = a3.z; o7 = a3.w;
    }

    // 16 per-cell accumulators -- NAMED scalars
    float x0=NEG,x1=NEG,x2=NEG,x3=NEG,x4=NEG,x5=NEG,x6=NEG,x7=NEG,
          x8=NEG,x9=NEG,x10=NEG,x11=NEG,x12=NEG,x13=NEG,x14=NEG,x15=NEG;

    // 8 px-pair groups; sched_barrier(0) fences the scheduler from merging
    // group live-ranges (per group: fe/fo/mw + 16 accumulators live).
    KITER(e0, o0, pa.x)  __builtin_amdgcn_sched_barrier(0);
    KITER(e1, o1, pa.y)  __builtin_amdgcn_sched_barrier(0);
    KITER(e2, o2, pa.z)  __builtin_amdgcn_sched_barrier(0);
    KITER(e3, o3, pa.w)  __builtin_amdgcn_sched_barrier(0);
    KITER(e4, o4, pb.x)  __builtin_amdgcn_sched_barrier(0);
    KITER(e5, o5, pb.y)  __builtin_amdgcn_sched_barrier(0);
    KITER(e6, o6, pb.z)  __builtin_amdgcn_sched_barrier(0);
    KITER(e7, o7, pb.w)

    // Fold-as-you-go butterfly (mapping verified R8..R12): after 4 folds lane
    // l holds cell (l&15); d=16,32 merge the 4 duplicate 16-lane groups.
    float y0,y1,y2,y3,y4,y5,y6,y7;
    {
        const bool s = (l & 1);
        FOLD(y0, x0,  x1,  s, 1)  FOLD(y1, x2,  x3,  s, 1)
        FOLD(y2, x4,  x5,  s, 1)  FOLD(y3, x6,  x7,  s, 1)
        FOLD(y4, x8,  x9,  s, 1)  FOLD(y5, x10, x11, s, 1)
        FOLD(y6, x12, x13, s, 1)  FOLD(y7, x14, x15, s, 1)
    }
    float z0,z1,z2,z3;
    {
        const bool s = ((l >> 1) & 1);
        FOLD(z0, y0, y1, s, 2)  FOLD(z1, y2, y3, s, 2)
        FOLD(z2, y4, y5, s, 2)  FOLD(z3, y6, y7, s, 2)
    }
    float t0,t1;
    {
        const bool s = ((l >> 2) & 1);
        FOLD(t0, z0, z1, s, 4)  FOLD(t1, z2, z3, s, 4)
    }
    float u;
    {
        const bool s = ((l >> 3) & 1);
        FOLD(u, t0, t1, s, 8)
    }
    u = fmaxf(u, __shfl_xor(u, 16, 64));
    u = fmaxf(u, __shfl_xor(u, 32, 64));

    // cross-wave combine: 4 waves x 16 cells, ONE barrier, 320 B LDS.
    __shared__ float red[4][16];
    if (l < 16) red[wv][l] = u;
    __syncthreads();
    if (tid < 16) {
        float m = fmaxf(fmaxf(red[0][tid], red[1][tid]),
                        fmaxf(red[2][tid], red[3][tid]));
        if (tid < cnt) {
            const size_t oi = (size_t)(start + tid) * CCH + c;
            if (fbf16) ((__hip_bfloat16*)outv)[oi] = __float2bfloat16(m);
            else       ((float*)outv)[oi]          = m;
        }
    }
}

extern "C" void kernel_launch(void* const* d_in, const int* in_sizes, int n_in,
                              void* d_out, int out_size, void* d_ws, size_t ws_size,
                              hipStream_t stream) {
    const void* feat  = d_in[0];
    const void* masks = d_in[1];
    const int* counts = (const int*)d_in[2];
    unsigned short* packed = (unsigned short*)d_ws;   // 8*4096*2 = 64 KiB

    pack_masks<<<(BIMG * HW) / 256, 256, 0, stream>>>(masks, counts, packed);

    dim3 grid(CCH, BIMG);   // 2048 blocks, one per (b, c)
    roipool_main<<<grid, 256, 0, stream>>>(feat, packed, counts, d_out);
}